// Round 3
// baseline (530.055 us; speedup 1.0000x reference)
//
#include <hip/hip_runtime.h>
#include <hip/hip_bf16.h>
#include <math.h>

// Problem constants
#define H   1024
#define Dd  200
#define Kc  8
#define Bb  8
#define Ll  4096
#define Mm  (Bb*Ll)  // 32768 rows

typedef __attribute__((ext_vector_type(8))) short short8;
typedef __attribute__((ext_vector_type(4))) float f32x4;

// ws layout (bytes)
#define OFF_W1T 0                      // bf16 [208][1024] = 425984 B
#define OFF_S   425984                 // f32 [Mm][8] = 1048576 B
#define WS_NEEDED (OFF_S + Mm*Kc*4)

#define GLOAD16(g, l) __builtin_amdgcn_global_load_lds( \
    (const __attribute__((address_space(1))) void*)(g),  \
    (__attribute__((address_space(3))) void*)(l), 16, 0, 0)

__device__ __forceinline__ unsigned short f2bf(float x){
  unsigned u = __float_as_uint(x);
  unsigned r = (u + 0x7FFFu + ((u >> 16) & 1u)) >> 16;   // RNE
  return (unsigned short)r;
}

// ---------------- prep: W1 (fp32 [H][Dd]) -> W1T (bf16 [208][H], zero-padded cols)
__global__ __launch_bounds__(256) void prep_w1t(const float* __restrict__ W1,
                                                unsigned short* __restrict__ W1T){
  int idx = blockIdx.x * 256 + threadIdx.x;   // 0 .. 208*1024-1
  int d = idx >> 10;
  int h = idx & 1023;
  float v = (d < Dd) ? W1[h * Dd + d] : 0.f;
  W1T[idx] = f2bf(v);
}

// ---------------- fused GEMM1 (bf16 MFMA) + tanh + GEMM2 + mean-scale -> s
// 512 thr = 8 waves: wr = wid>>1 (16-row group of BM=64), wc = wid&1 (N-half).
// B (W1T) double-buffered in LDS via global_load_lds, XOR-swizzled (write via
// pre-swizzled SOURCE, read via same XOR — rule #21). A straight from global
// (lane frag = 32B contiguous). Counted vmcnt(8), never 0 in main loop (T4).
__global__ __launch_bounds__(512, 4) void gemm_fused(const float* __restrict__ hidd,
                                                     const unsigned short* __restrict__ W1T,
                                                     const float* __restrict__ b1,
                                                     const float* __restrict__ W2,
                                                     const float* __restrict__ b2,
                                                     float* __restrict__ sOut){
  __shared__ char lB[2 * 32768];        // 2 buffers x [256 cols][128 B]
  __shared__ float epart[8][4][4][8];   // [wid][lg][r][k]
  __shared__ float lrow[64];

  const int tid  = threadIdx.x;
  const int lane = tid & 63;
  const int wid  = tid >> 6;
  const int lc   = lane & 15;
  const int lg   = lane >> 4;
  const int wr   = wid >> 1;       // row group (16 rows)
  const int wc   = wid & 1;        // N half: t 0..6 / 7..12
  const int t0   = wc * 7;
  const int ntw  = 7 - wc;
  const long rowBase = (long)blockIdx.x * 64;

  const float* ap = hidd + (size_t)(rowBase + wr * 16 + lc) * H + lg * 8;

  // B staging: wave wid owns chunks wid*4+j (j=0..3); chunk = 8 cols x 128 B.
  // lane l -> col = chunkBase + (l>>3), within-col byte (l&7)*16, source
  // pre-swizzled by ((l&7)^(l>>3))<<4 so swizzled READS see correct data.
  const int swz = (((lane & 7) ^ (lane >> 3)) & 7) * 16;
  const char* bsrcj[4];
  #pragma unroll
  for (int j = 0; j < 4; ++j){
    int colj = wid * 32 + j * 8 + (lane >> 3);
    colj = (colj < 207) ? colj : 207;              // clamp pad cols (never read)
    bsrcj[j] = (const char*)W1T + (size_t)colj * 2048 + swz;
  }

  // prologue: A for kt=0, B for kt=0 into buf0
  float4 pf[2][4];
  #pragma unroll
  for (int x = 0; x < 4; ++x)
    pf[0][x] = *(const float4*)(ap + (x >> 1) * 32 + (x & 1) * 4);
  #pragma unroll
  for (int j = 0; j < 4; ++j)
    GLOAD16(bsrcj[j], &lB[wid * 4096 + j * 1024]);

  f32x4 acc[7];
  #pragma unroll
  for (int t = 0; t < 7; ++t) acc[t] = (f32x4){0.f, 0.f, 0.f, 0.f};
  float ms = 0.f;

  #pragma unroll
  for (int kt = 0; kt < 16; ++kt){
    const int cur = kt & 1, nxt = cur ^ 1;
    if (kt < 15){
      #pragma unroll
      for (int x = 0; x < 4; ++x)
        pf[nxt][x] = *(const float4*)(ap + (kt + 1) * 64 + (x >> 1) * 32 + (x & 1) * 4);
      #pragma unroll
      for (int j = 0; j < 4; ++j)
        GLOAD16(bsrcj[j] + (kt + 1) * 128, &lB[nxt * 32768 + wid * 4096 + j * 1024]);
      // keep the 8 newest (A_{kt+1}, B_{kt+1}) in flight; drain B_kt (oldest)
      asm volatile("s_waitcnt vmcnt(8)" ::: "memory");
    } else {
      asm volatile("s_waitcnt vmcnt(0)" ::: "memory");
    }
    __builtin_amdgcn_s_barrier();
    __builtin_amdgcn_sched_barrier(0);

    const float4 a0 = pf[cur][0], a1 = pf[cur][1], a2 = pf[cur][2], a3 = pf[cur][3];
    ms += a0.x + a0.y + a0.z + a0.w + a1.x + a1.y + a1.z + a1.w
        + a2.x + a2.y + a2.z + a2.w + a3.x + a3.y + a3.z + a3.w;
    union Uc { short8 s8; __hip_bfloat162 h2[4]; };
    Uc u0, u1;
    u0.h2[0] = __float22bfloat162_rn(make_float2(a0.x, a0.y));
    u0.h2[1] = __float22bfloat162_rn(make_float2(a0.z, a0.w));
    u0.h2[2] = __float22bfloat162_rn(make_float2(a1.x, a1.y));
    u0.h2[3] = __float22bfloat162_rn(make_float2(a1.z, a1.w));
    u1.h2[0] = __float22bfloat162_rn(make_float2(a2.x, a2.y));
    u1.h2[1] = __float22bfloat162_rn(make_float2(a2.z, a2.w));
    u1.h2[2] = __float22bfloat162_rn(make_float2(a3.x, a3.y));
    u1.h2[3] = __float22bfloat162_rn(make_float2(a3.z, a3.w));

    const char* bb = &lB[cur * 32768];
    #pragma unroll
    for (int tt = 0; tt < 7; ++tt){
      if (tt < ntw){
        const int col = (t0 + tt) * 16 + lc;
        const int cs  = (col & 7) * 16;
        const short8 bf0 = *(const short8*)(bb + col * 128 + (( 0 + lg * 16) ^ cs));
        const short8 bf1 = *(const short8*)(bb + col * 128 + ((64 + lg * 16) ^ cs));
        acc[tt] = __builtin_amdgcn_mfma_f32_16x16x32_bf16(u0.s8, bf0, acc[tt], 0, 0, 0);
        acc[tt] = __builtin_amdgcn_mfma_f32_16x16x32_bf16(u1.s8, bf1, acc[tt], 0, 0, 0);
      }
    }
    if (kt < 15){
      __builtin_amdgcn_sched_barrier(0);
      __builtin_amdgcn_s_barrier();      // readers done before next iter overwrites buf[cur]
      __builtin_amdgcn_sched_barrier(0);
    }
  }

  // row means: lane(lc,lg) holds partial over its k-slices; reduce over lg
  ms += __shfl_xor(ms, 16);
  ms += __shfl_xor(ms, 32);
  if (wc == 0 && lane < 16) lrow[wr * 16 + lane] = ms * (1.0f / 1024.0f);

  // epilogue: tanh + GEMM2 (in-register) + butterfly over lc
  float part[4][Kc];
  #pragma unroll
  for (int r = 0; r < 4; ++r)
    #pragma unroll
    for (int k = 0; k < Kc; ++k) part[r][k] = 0.f;

  #pragma unroll
  for (int tt = 0; tt < 7; ++tt){
    if (tt < ntw){
      const int col = (t0 + tt) * 16 + lc;
      float b1v = 0.f;
      float w2v[Kc];
      if (col < Dd){
        b1v = b1[col];
        const float4 wa = *(const float4*)(W2 + col * Kc);
        const float4 wb = *(const float4*)(W2 + col * Kc + 4);
        w2v[0] = wa.x; w2v[1] = wa.y; w2v[2] = wa.z; w2v[3] = wa.w;
        w2v[4] = wb.x; w2v[5] = wb.y; w2v[6] = wb.z; w2v[7] = wb.w;
      } else {
        #pragma unroll
        for (int k = 0; k < Kc; ++k) w2v[k] = 0.f;
      }
      #pragma unroll
      for (int r = 0; r < 4; ++r){
        const float a = tanhf(acc[tt][r] + b1v);
        #pragma unroll
        for (int k = 0; k < Kc; ++k) part[r][k] = fmaf(a, w2v[k], part[r][k]);
      }
    }
  }
  #pragma unroll
  for (int m = 1; m < 16; m <<= 1){
    #pragma unroll
    for (int r = 0; r < 4; ++r)
      #pragma unroll
      for (int k = 0; k < Kc; ++k)
        part[r][k] += __shfl_xor(part[r][k], m);
  }
  if ((lane & 15) == 0){
    #pragma unroll
    for (int r = 0; r < 4; ++r)
      #pragma unroll
      for (int k = 0; k < Kc; ++k)
        epart[wid][lg][r][k] = part[r][k];
  }
  __syncthreads();

  // combine the two wc halves, add b2, scale by row mean, store (coalesced)
  {
    const int row2 = tid >> 3, k = tid & 7;
    const int wr2 = row2 >> 4, lg2 = (row2 >> 2) & 3, r2 = row2 & 3;
    const float v = epart[wr2 * 2][lg2][r2][k] + epart[wr2 * 2 + 1][lg2][r2][k];
    sOut[(size_t)(rowBase + row2) * Kc + k] = (v + b2[k]) * lrow[row2];
  }
}

// ---------------- per-batch fused: seg sums + scan + det + softmax + loss
__global__ __launch_bounds__(256) void tail_loss(const float* __restrict__ s,
                                                 const int* __restrict__ ptypes,
                                                 const int* __restrict__ labels,
                                                 float* __restrict__ out){
  const int b = blockIdx.x;
  const int tid = threadIdx.x, lane = tid & 63, wid = tid >> 6;
  __shared__ float segtot[16][8];
  __shared__ float wtmp[4][8];
  __shared__ float red[4];
  const float* sb = s + (size_t)b * Ll * Kc;

  // pass 1: per-segment channel totals
  for (int seg = 0; seg < 16; ++seg){
    const float4* sp = (const float4*)(sb + (size_t)(seg * 256 + tid) * Kc);
    const float4 v0 = sp[0], v1 = sp[1];
    float v[8] = {v0.x, v0.y, v0.z, v0.w, v1.x, v1.y, v1.z, v1.w};
    #pragma unroll
    for (int k = 0; k < 8; ++k){
      float x = v[k];
      x += __shfl_xor(x, 1);  x += __shfl_xor(x, 2);  x += __shfl_xor(x, 4);
      x += __shfl_xor(x, 8);  x += __shfl_xor(x, 16); x += __shfl_xor(x, 32);
      v[k] = x;
    }
    if (lane == 0){
      #pragma unroll
      for (int k = 0; k < 8; ++k) wtmp[wid][k] = v[k];
    }
    __syncthreads();
    if (tid < 8) segtot[seg][tid] = wtmp[0][tid] + wtmp[1][tid] + wtmp[2][tid] + wtmp[3][tid];
    __syncthreads();
  }

  float T[8];
  #pragma unroll
  for (int k = 0; k < 8; ++k) T[k] = 0.f;
  for (int seg = 0; seg < 16; ++seg)
    #pragma unroll
    for (int k = 0; k < 8; ++k) T[k] += segtot[seg][k];

  const int pt = ptypes[b];
  float carry[8];
  #pragma unroll
  for (int k = 0; k < 8; ++k) carry[k] = 0.f;
  float lossAcc = 0.f;
  __shared__ float wsum[4][8];

  // pass 2: scan + loss
  for (int seg = 0; seg < 16; ++seg){
    const int l = seg * 256 + tid;
    const float4* sp = (const float4*)(sb + (size_t)l * Kc);
    const float4 v0 = sp[0], v1 = sp[1];
    float sv[8] = {v0.x, v0.y, v0.z, v0.w, v1.x, v1.y, v1.z, v1.w};
    float P[8];
    #pragma unroll
    for (int k = 0; k < 8; ++k) P[k] = sv[k];
    #pragma unroll
    for (int st = 1; st < 64; st <<= 1){
      #pragma unroll
      for (int k = 0; k < 8; ++k){
        const float u = __shfl_up(P[k], st);
        if (lane >= st) P[k] += u;
      }
    }
    if (lane == 63){
      #pragma unroll
      for (int k = 0; k < 8; ++k) wsum[wid][k] = P[k];
    }
    __syncthreads();
    for (int w = 0; w < wid; ++w)
      #pragma unroll
      for (int k = 0; k < 8; ++k) P[k] += wsum[w][k];
    #pragma unroll
    for (int k = 0; k < 8; ++k) P[k] += carry[k];

    float det[8];
    if (pt == 0){
      const float inv = 1.0f / (float)(l + 1);
      #pragma unroll
      for (int k = 0; k < 8; ++k) det[k] = P[k] * inv;
    } else if (pt == 1){
      const float inv = 1.0f / (float)(Ll - l);
      #pragma unroll
      for (int k = 0; k < 8; ++k) det[k] = (T[k] - P[k] + sv[k]) * inv;
    } else {
      #pragma unroll
      for (int k = 0; k < 8; ++k) det[k] = sv[k];
    }

    float mx = det[0];
    #pragma unroll
    for (int k = 1; k < 8; ++k) mx = fmaxf(mx, det[k]);
    float e[8], Z = 0.f;
    #pragma unroll
    for (int k = 0; k < 8; ++k){ e[k] = expf(det[k] - mx); Z += e[k]; }
    const float invZ = 1.0f / Z;
    float p[8];
    #pragma unroll
    for (int k = 0; k < 8; ++k) p[k] = e[k] * invZ;
    float mx2 = p[0];
    #pragma unroll
    for (int k = 1; k < 8; ++k) mx2 = fmaxf(mx2, p[k]);
    float Z2 = 0.f;
    #pragma unroll
    for (int k = 0; k < 8; ++k) Z2 += expf(p[k] - mx2);
    const float lse = logf(Z2) + mx2;

    const int lab = labels[b * Ll + l];
    #pragma unroll
    for (int k = 0; k < 8; ++k) if (lab == k) lossAcc += (p[k] - lse);

    #pragma unroll
    for (int k = 0; k < 8; ++k) carry[k] += segtot[seg][k];
    __syncthreads();
  }

  float a = lossAcc;
  a += __shfl_xor(a, 1);  a += __shfl_xor(a, 2);  a += __shfl_xor(a, 4);
  a += __shfl_xor(a, 8);  a += __shfl_xor(a, 16); a += __shfl_xor(a, 32);
  if (lane == 0) red[wid] = a;
  __syncthreads();
  if (tid == 0) out[b] = -(red[0] + red[1] + red[2] + red[3]) * (1.0f / (float)Ll);
}

extern "C" void kernel_launch(void* const* d_in, const int* in_sizes, int n_in,
                              void* d_out, int out_size, void* d_ws, size_t ws_size,
                              hipStream_t stream){
  const float* hidd  = (const float*)d_in[0];
  const float* W1    = (const float*)d_in[1];
  const float* b1    = (const float*)d_in[2];
  const float* W2    = (const float*)d_in[3];
  const float* b2    = (const float*)d_in[4];
  const int* ptypes  = (const int*)d_in[5];
  const int* labels  = (const int*)d_in[6];
  float* out = (float*)d_out;
  char* ws = (char*)d_ws;
  if (ws_size < (size_t)WS_NEEDED) return;

  unsigned short* W1T = (unsigned short*)(ws + OFF_W1T);
  float* s = (float*)(ws + OFF_S);

  prep_w1t<<<(208 * H) / 256, 256, 0, stream>>>(W1, W1T);
  gemm_fused<<<Mm / 64, 512, 0, stream>>>(hidd, W1T, b1, W2, b2, s);
  tail_loss<<<Bb, 256, 0, stream>>>(s, ptypes, labels, out);
}

// Round 4
// 237.419 us; speedup vs baseline: 2.2326x; 2.2326x over previous
//
#include <hip/hip_runtime.h>
#include <hip/hip_bf16.h>
#include <math.h>

// Problem constants
#define H   1024
#define Dd  200
#define Kc  8
#define Bb  8
#define Ll  4096
#define Mm  (Bb*Ll)  // 32768 rows

typedef __attribute__((ext_vector_type(8))) short short8;
typedef __attribute__((ext_vector_type(4))) float f32x4;

// ws layout (bytes)
#define OFF_W1T  0                           // bf16 [208][1024] = 425984 B
#define OFF_S    425984                      // f32 [Mm][8]     = 1048576 B
#define OFF_SEG  (OFF_S + Mm*Kc*4)           // f32 [8][16][8]  = 4096 B
#define OFF_PART (OFF_SEG + Bb*16*Kc*4)      // f32 [128]
#define WS_NEEDED (OFF_PART + 128*4)

#define GLOAD16(g, l) __builtin_amdgcn_global_load_lds( \
    (const __attribute__((address_space(1))) void*)(g),  \
    (__attribute__((address_space(3))) void*)(l), 16, 0, 0)

__device__ __forceinline__ unsigned short f2bf(float x){
  unsigned u = __float_as_uint(x);
  unsigned r = (u + 0x7FFFu + ((u >> 16) & 1u)) >> 16;   // RNE
  return (unsigned short)r;
}

// ---------------- prep: W1 (fp32 [H][Dd]) -> W1T (bf16 [208][H], zero-padded cols)
__global__ __launch_bounds__(256) void prep_w1t(const float* __restrict__ W1,
                                                unsigned short* __restrict__ W1T){
  int idx = blockIdx.x * 256 + threadIdx.x;   // 0 .. 208*1024-1
  int d = idx >> 10;
  int h = idx & 1023;
  float v = (d < Dd) ? W1[h * Dd + d] : 0.f;
  W1T[idx] = f2bf(v);
}

// ---------------- fused GEMM1 (bf16 MFMA) + tanh + GEMM2 + mean-scale -> s
// 512 thr = 8 waves: wr = wid>>1 (16-row group of BM=64), wc = wid&1 (N-half).
// B (W1T) double-buffered in LDS via global_load_lds, XOR-swizzled (write via
// pre-swizzled SOURCE, read via same XOR — rule #21). A straight from global
// into regs, single prefetch buffer. Counted vmcnt: never 0 in main loop.
// waves_per_eu(4) caps VGPR at 128 -> 2 blocks/CU (LDS 70KB x2 = 140 < 160).
__global__ __launch_bounds__(512) __attribute__((amdgpu_waves_per_eu(4)))
void gemm_fused(const float* __restrict__ hidd,
                const unsigned short* __restrict__ W1T,
                const float* __restrict__ b1,
                const float* __restrict__ W2,
                const float* __restrict__ b2,
                float* __restrict__ sOut){
  __shared__ char lB[2 * 32768];        // 2 buffers x [256 cols][128 B]
  __shared__ float epart[8][4][4][8];   // [wid][lg][r][k]
  __shared__ float lrow[64];

  const int tid  = threadIdx.x;
  const int lane = tid & 63;
  const int wid  = tid >> 6;
  const int lc   = lane & 15;
  const int lg   = lane >> 4;
  const int wr   = wid >> 1;       // row group (16 rows)
  const int wc   = wid & 1;        // N half: t 0..6 / 7..12
  const int t0   = wc * 7;
  const int ntw  = 7 - wc;
  const long rowBase = (long)blockIdx.x * 64;

  const float* ap = hidd + (size_t)(rowBase + wr * 16 + lc) * H + lg * 8;

  // B staging: wave wid owns chunks wid*4+j (j=0..3); chunk = 8 cols x 128 B.
  // lane l -> col = chunkBase + (l>>3), within-col byte (l&7)*16, source
  // pre-swizzled by ((l&7)^(l>>3))<<4 so swizzled READS see correct data.
  const int swz = (((lane & 7) ^ (lane >> 3)) & 7) * 16;
  const char* bsrcj[4];
  #pragma unroll
  for (int j = 0; j < 4; ++j){
    int colj = wid * 32 + j * 8 + (lane >> 3);
    colj = (colj < 207) ? colj : 207;              // clamp pad cols (never read)
    bsrcj[j] = (const char*)W1T + (size_t)colj * 2048 + swz;
  }

  // prologue: A(0) into pf, B(0) into buf0   (8 VMEM ops in flight)
  float4 pf[4];
  #pragma unroll
  for (int x = 0; x < 4; ++x)
    pf[x] = *(const float4*)(ap + (x >> 1) * 32 + (x & 1) * 4);
  #pragma unroll
  for (int j = 0; j < 4; ++j)
    GLOAD16(bsrcj[j], &lB[wid * 4096 + j * 1024]);

  f32x4 acc[7];
  #pragma unroll
  for (int t = 0; t < 7; ++t) acc[t] = (f32x4){0.f, 0.f, 0.f, 0.f};
  float ms = 0.f;

  #pragma unroll 2
  for (int kt = 0; kt < 16; ++kt){
    const int cur = kt & 1, nxt = cur ^ 1;

    // A(kt) has landed once <=4 newest (the B(kt) GLOADs) remain in flight
    asm volatile("s_waitcnt vmcnt(4)" ::: "memory");
    const float4 a0 = pf[0], a1 = pf[1], a2 = pf[2], a3 = pf[3];
    ms += a0.x + a0.y + a0.z + a0.w + a1.x + a1.y + a1.z + a1.w
        + a2.x + a2.y + a2.z + a2.w + a3.x + a3.y + a3.z + a3.w;
    union Uc { short8 s8; __hip_bfloat162 h2[4]; };
    Uc u0, u1;
    u0.h2[0] = __float22bfloat162_rn(make_float2(a0.x, a0.y));
    u0.h2[1] = __float22bfloat162_rn(make_float2(a0.z, a0.w));
    u0.h2[2] = __float22bfloat162_rn(make_float2(a1.x, a1.y));
    u0.h2[3] = __float22bfloat162_rn(make_float2(a1.z, a1.w));
    u1.h2[0] = __float22bfloat162_rn(make_float2(a2.x, a2.y));
    u1.h2[1] = __float22bfloat162_rn(make_float2(a2.z, a2.w));
    u1.h2[2] = __float22bfloat162_rn(make_float2(a3.x, a3.y));
    u1.h2[3] = __float22bfloat162_rn(make_float2(a3.z, a3.w));

    if (kt < 15){
      // issue next tile: A(kt+1) -> pf (WAR ok, pf already consumed),
      // B(kt+1) -> lB[nxt] (safe: end-of-iter barrier of kt-1 passed)
      #pragma unroll
      for (int x = 0; x < 4; ++x)
        pf[x] = *(const float4*)(ap + (kt + 1) * 64 + (x >> 1) * 32 + (x & 1) * 4);
      #pragma unroll
      for (int j = 0; j < 4; ++j)
        GLOAD16(bsrcj[j] + (kt + 1) * 128, &lB[nxt * 32768 + wid * 4096 + j * 1024]);
      // drain B(kt) (keep the 8 newest: A(kt+1)+B(kt+1))
      asm volatile("s_waitcnt vmcnt(8)" ::: "memory");
    } else {
      asm volatile("s_waitcnt vmcnt(0)" ::: "memory");
    }
    __builtin_amdgcn_s_barrier();
    __builtin_amdgcn_sched_barrier(0);

    const char* bb = &lB[cur * 32768];
    #pragma unroll
    for (int tt = 0; tt < 7; ++tt){
      if (tt < ntw){
        const int col = (t0 + tt) * 16 + lc;
        const int cs  = (col & 7) * 16;
        const short8 bf0 = *(const short8*)(bb + col * 128 + (( 0 + lg * 16) ^ cs));
        const short8 bf1 = *(const short8*)(bb + col * 128 + ((64 + lg * 16) ^ cs));
        acc[tt] = __builtin_amdgcn_mfma_f32_16x16x32_bf16(u0.s8, bf0, acc[tt], 0, 0, 0);
        acc[tt] = __builtin_amdgcn_mfma_f32_16x16x32_bf16(u1.s8, bf1, acc[tt], 0, 0, 0);
      }
    }
    if (kt < 15){
      __builtin_amdgcn_sched_barrier(0);
      __builtin_amdgcn_s_barrier();      // readers done before kt+1 overwrites lB[cur]
      __builtin_amdgcn_sched_barrier(0);
    }
  }

  // row means: lane(lc,lg) holds partial over its k-slices; reduce over lg
  ms += __shfl_xor(ms, 16);
  ms += __shfl_xor(ms, 32);
  if (wc == 0 && lane < 16) lrow[wr * 16 + lane] = ms * (1.0f / 1024.0f);

  // epilogue: tanh + GEMM2 (in-register) + butterfly over lc
  float part[4][Kc];
  #pragma unroll
  for (int r = 0; r < 4; ++r)
    #pragma unroll
    for (int k = 0; k < Kc; ++k) part[r][k] = 0.f;

  #pragma unroll
  for (int tt = 0; tt < 7; ++tt){
    if (tt < ntw){
      const int col = (t0 + tt) * 16 + lc;
      float b1v = 0.f;
      float w2v[Kc];
      if (col < Dd){
        b1v = b1[col];
        const float4 wa = *(const float4*)(W2 + col * Kc);
        const float4 wb = *(const float4*)(W2 + col * Kc + 4);
        w2v[0] = wa.x; w2v[1] = wa.y; w2v[2] = wa.z; w2v[3] = wa.w;
        w2v[4] = wb.x; w2v[5] = wb.y; w2v[6] = wb.z; w2v[7] = wb.w;
      } else {
        #pragma unroll
        for (int k = 0; k < Kc; ++k) w2v[k] = 0.f;
      }
      #pragma unroll
      for (int r = 0; r < 4; ++r){
        const float a = tanhf(acc[tt][r] + b1v);
        #pragma unroll
        for (int k = 0; k < Kc; ++k) part[r][k] = fmaf(a, w2v[k], part[r][k]);
      }
    }
  }
  #pragma unroll
  for (int m = 1; m < 16; m <<= 1){
    #pragma unroll
    for (int r = 0; r < 4; ++r)
      #pragma unroll
      for (int k = 0; k < Kc; ++k)
        part[r][k] += __shfl_xor(part[r][k], m);
  }
  if ((lane & 15) == 0){
    #pragma unroll
    for (int r = 0; r < 4; ++r)
      #pragma unroll
      for (int k = 0; k < Kc; ++k)
        epart[wid][lg][r][k] = part[r][k];
  }
  __syncthreads();

  // combine the two wc halves, add b2, scale by row mean, store (coalesced)
  {
    const int row2 = tid >> 3, k = tid & 7;
    const int wr2 = row2 >> 4, lg2 = (row2 >> 2) & 3, r2 = row2 & 3;
    const float v = epart[wr2 * 2][lg2][r2][k] + epart[wr2 * 2 + 1][lg2][r2][k];
    sOut[(size_t)(rowBase + row2) * Kc + k] = (v + b2[k]) * lrow[row2];
  }
}

// ---------------- per-(batch,segment) channel sums
__global__ __launch_bounds__(256) void seg_sum(const float* __restrict__ s,
                                               float* __restrict__ segs){
  int b   = blockIdx.x >> 4;
  int seg = blockIdx.x & 15;
  int tid = threadIdx.x, lane = tid & 63, wid = tid >> 6;
  int l = seg * 256 + tid;
  const float4* sp = (const float4*)(s + ((long)(b * Ll + l)) * Kc);
  float4 v0 = sp[0], v1 = sp[1];
  float v[8] = {v0.x, v0.y, v0.z, v0.w, v1.x, v1.y, v1.z, v1.w};
  #pragma unroll
  for (int k = 0; k < 8; ++k){
    float x = v[k];
    x += __shfl_xor(x, 1);  x += __shfl_xor(x, 2);  x += __shfl_xor(x, 4);
    x += __shfl_xor(x, 8);  x += __shfl_xor(x, 16); x += __shfl_xor(x, 32);
    v[k] = x;
  }
  __shared__ float part[4][8];
  if (lane == 0){
    #pragma unroll
    for (int k = 0; k < 8; ++k) part[wid][k] = v[k];
  }
  __syncthreads();
  if (tid < 8){
    float t = part[0][tid] + part[1][tid] + part[2][tid] + part[3][tid];
    segs[(b * 16 + seg) * 8 + tid] = t;
  }
}

// ---------------- scan + det + softmax + log_softmax + pick -> partial loss
__global__ __launch_bounds__(256) void scan_loss(const float* __restrict__ s,
                                                 const float* __restrict__ segs,
                                                 const int* __restrict__ ptypes,
                                                 const int* __restrict__ labels,
                                                 float* __restrict__ partial){
  int b   = blockIdx.x >> 4;
  int seg = blockIdx.x & 15;
  int tid = threadIdx.x, lane = tid & 63, wid = tid >> 6;
  int l = seg * 256 + tid;

  float carry[8], T[8];
  #pragma unroll
  for (int k = 0; k < 8; ++k){ carry[k] = 0.f; T[k] = 0.f; }
  for (int ss = 0; ss < 16; ++ss){
    #pragma unroll
    for (int k = 0; k < 8; ++k){
      float x = segs[(b * 16 + ss) * 8 + k];
      T[k] += x;
      if (ss < seg) carry[k] += x;
    }
  }

  const float4* sp = (const float4*)(s + ((long)(b * Ll + l)) * Kc);
  float4 v0 = sp[0], v1 = sp[1];
  float sv[8] = {v0.x, v0.y, v0.z, v0.w, v1.x, v1.y, v1.z, v1.w};
  float P[8];
  #pragma unroll
  for (int k = 0; k < 8; ++k) P[k] = sv[k];

  #pragma unroll
  for (int st = 1; st < 64; st <<= 1){
    #pragma unroll
    for (int k = 0; k < 8; ++k){
      float u = __shfl_up(P[k], st);
      if (lane >= st) P[k] += u;
    }
  }
  __shared__ float wsum[4][8];
  if (lane == 63){
    #pragma unroll
    for (int k = 0; k < 8; ++k) wsum[wid][k] = P[k];
  }
  __syncthreads();
  for (int w = 0; w < wid; ++w){
    #pragma unroll
    for (int k = 0; k < 8; ++k) P[k] += wsum[w][k];
  }
  #pragma unroll
  for (int k = 0; k < 8; ++k) P[k] += carry[k];

  int pt = ptypes[b];
  float det[8];
  if (pt == 0){
    float inv = 1.0f / (float)(l + 1);
    #pragma unroll
    for (int k = 0; k < 8; ++k) det[k] = P[k] * inv;
  } else if (pt == 1){
    float inv = 1.0f / (float)(Ll - l);
    #pragma unroll
    for (int k = 0; k < 8; ++k) det[k] = (T[k] - P[k] + sv[k]) * inv;
  } else {
    #pragma unroll
    for (int k = 0; k < 8; ++k) det[k] = sv[k];
  }

  float mx = det[0];
  #pragma unroll
  for (int k = 1; k < 8; ++k) mx = fmaxf(mx, det[k]);
  float e[8], Z = 0.f;
  #pragma unroll
  for (int k = 0; k < 8; ++k){ e[k] = expf(det[k] - mx); Z += e[k]; }
  float invZ = 1.0f / Z;
  float p[8];
  #pragma unroll
  for (int k = 0; k < 8; ++k) p[k] = e[k] * invZ;
  float mx2 = p[0];
  #pragma unroll
  for (int k = 1; k < 8; ++k) mx2 = fmaxf(mx2, p[k]);
  float Z2 = 0.f;
  #pragma unroll
  for (int k = 0; k < 8; ++k) Z2 += expf(p[k] - mx2);
  float lse = logf(Z2) + mx2;

  int lab = labels[b * Ll + l];
  float picked = 0.f;
  #pragma unroll
  for (int k = 0; k < 8; ++k) picked = (lab == k) ? (p[k] - lse) : picked;

  float a = picked;
  a += __shfl_xor(a, 1);  a += __shfl_xor(a, 2);  a += __shfl_xor(a, 4);
  a += __shfl_xor(a, 8);  a += __shfl_xor(a, 16); a += __shfl_xor(a, 32);
  __shared__ float red[4];
  if (lane == 0) red[wid] = a;
  __syncthreads();
  if (tid == 0){
    partial[blockIdx.x] = red[0] + red[1] + red[2] + red[3];
  }
}

// ---------------- final: out[b] = -sum(partial[b*16 .. +15]) / L
__global__ __launch_bounds__(128) void final_loss(const float* __restrict__ partial,
                                                  float* __restrict__ out){
  int tid = threadIdx.x;  // 0..127 -> b = tid>>4
  float v = partial[tid];
  v += __shfl_xor(v, 1); v += __shfl_xor(v, 2);
  v += __shfl_xor(v, 4); v += __shfl_xor(v, 8);
  if ((tid & 15) == 0) out[tid >> 4] = -v * (1.0f / (float)Ll);
}

extern "C" void kernel_launch(void* const* d_in, const int* in_sizes, int n_in,
                              void* d_out, int out_size, void* d_ws, size_t ws_size,
                              hipStream_t stream){
  const float* hidd  = (const float*)d_in[0];
  const float* W1    = (const float*)d_in[1];
  const float* b1    = (const float*)d_in[2];
  const float* W2    = (const float*)d_in[3];
  const float* b2    = (const float*)d_in[4];
  const int* ptypes  = (const int*)d_in[5];
  const int* labels  = (const int*)d_in[6];
  float* out = (float*)d_out;
  char* ws = (char*)d_ws;
  if (ws_size < (size_t)WS_NEEDED) return;

  unsigned short* W1T = (unsigned short*)(ws + OFF_W1T);
  float* s       = (float*)(ws + OFF_S);
  float* segs    = (float*)(ws + OFF_SEG);
  float* partial = (float*)(ws + OFF_PART);

  prep_w1t<<<(208 * H) / 256, 256, 0, stream>>>(W1, W1T);
  gemm_fused<<<Mm / 64, 512, 0, stream>>>(hidd, W1T, b1, W2, b2, s);
  seg_sum<<<Bb * 16, 256, 0, stream>>>(s, segs);
  scan_loss<<<Bb * 16, 256, 0, stream>>>(s, segs, ptypes, labels, partial);
  final_loss<<<1, 128, 0, stream>>>(partial, out);
}

// Round 5
// 229.858 us; speedup vs baseline: 2.3060x; 1.0329x over previous
//
#include <hip/hip_runtime.h>
#include <hip/hip_bf16.h>
#include <math.h>

// Problem constants
#define H   1024
#define Dd  200
#define Kc  8
#define Bb  8
#define Ll  4096
#define Mm  (Bb*Ll)  // 32768 rows

typedef __attribute__((ext_vector_type(8))) short short8;
typedef __attribute__((ext_vector_type(4))) float f32x4;

// ws layout (bytes)
#define OFF_W1T  0                           // bf16 [208][1024] = 425984 B
#define OFF_S    425984                      // f32 [Mm][8]     = 1048576 B
#define OFF_SEG  (OFF_S + Mm*Kc*4)           // f32 [8][16][8]  = 4096 B
#define OFF_PART (OFF_SEG + Bb*16*Kc*4)      // f32 [128]
#define WS_NEEDED (OFF_PART + 128*4)

#define GLOAD16(g, l) __builtin_amdgcn_global_load_lds( \
    (const __attribute__((address_space(1))) void*)(g),  \
    (__attribute__((address_space(3))) void*)(l), 16, 0, 0)

__device__ __forceinline__ unsigned short f2bf(float x){
  unsigned u = __float_as_uint(x);
  unsigned r = (u + 0x7FFFu + ((u >> 16) & 1u)) >> 16;   // RNE
  return (unsigned short)r;
}

union Uc { short8 s8; __hip_bfloat162 h2[4]; };

// ---------------- prep: W1 (fp32 [H][Dd]) -> W1T (bf16 [208][H], zero-padded cols)
__global__ __launch_bounds__(256) void prep_w1t(const float* __restrict__ W1,
                                                unsigned short* __restrict__ W1T){
  int idx = blockIdx.x * 256 + threadIdx.x;   // 0 .. 208*1024-1
  int d = idx >> 10;
  int h = idx & 1023;
  float v = (d < Dd) ? W1[h * Dd + d] : 0.f;
  W1T[idx] = f2bf(v);
}

// ---------------- fused GEMM1 (bf16 MFMA) + tanh + GEMM2 + mean-scale -> s
// 512 thr = 8 waves: wr = wid>>1 (16-row group of BM=64), wc = wid&1 (N-half).
// A: coalesced global float4 -> reg -> cvt bf16 -> ds_write_b128 into 8 KB
//    single-buffer LDS tile [64 rows][128 B], XOR-swizzled byte^=(row&7)<<4.
//    (R2/R4's per-lane scattered A-loads — 64 cache lines per instr — were
//    the latency killer; staging makes them coalesced.)
// B: double-buffered global_load_lds, pre-swizzled source (rule #21).
// Counted vmcnt(6) in main loop, never 0 (T4). 2 blocks/CU (LDS 76 KB).
__global__ __launch_bounds__(512) __attribute__((amdgpu_waves_per_eu(4)))
void gemm_fused(const float* __restrict__ hidd,
                const unsigned short* __restrict__ W1T,
                const float* __restrict__ b1,
                const float* __restrict__ W2,
                const float* __restrict__ b2,
                float* __restrict__ sOut){
  __shared__ char lA[64 * 128];         // bf16 [row][64k], swizzled
  __shared__ char lB[2 * 32768];        // 2 buffers x [256 cols][128 B]
  __shared__ float epart[8][4][4][8];   // [wid][lg][r][k]
  __shared__ float lrow[64];
  char* lAc = lA;

  const int tid  = threadIdx.x;
  const int lane = tid & 63;
  const int wid  = tid >> 6;
  const int lc   = lane & 15;
  const int lg   = lane >> 4;
  const int wr   = wid >> 1;       // row group (16 rows)
  const int wc   = wid & 1;        // N half: tiles 0..6 / 7..12
  const int t0   = wc * 7;
  const int ntw  = 7 - wc;
  const long rowBase = (long)blockIdx.x * 64;

  // A staging: thread t -> row t>>3 (0..63), k8 = t&7 (8-float group).
  // Global: 8 threads cover one row's 256 B contiguous -> coalesced.
  const int arow = tid >> 3, ak8 = tid & 7;
  const float* ag = hidd + (size_t)(rowBase + arow) * H + ak8 * 8;
  const int awb = ((arow * 128 + ak8 * 16) ^ ((arow & 7) << 4));  // LDS write byte

  // B staging (proven R4 path): wave wid owns chunks wid*4+j; pre-swizzled src.
  const int swz = (((lane & 7) ^ (lane >> 3)) & 7) * 16;
  const char* bsrcj[4];
  #pragma unroll
  for (int j = 0; j < 4; ++j){
    int colj = wid * 32 + j * 8 + (lane >> 3);
    colj = (colj < 207) ? colj : 207;              // clamp pad cols (never read)
    bsrcj[j] = (const char*)W1T + (size_t)colj * 2048 + swz;
  }

  // A fragment read offsets (1 x ds_read_b128 per k-half)
  const int acs   = (lc & 7) << 4;
  const int aoff0 = (wr * 16 + lc) * 128 + ((lg * 16) ^ acs);
  const int aoff1 = (wr * 16 + lc) * 128 + (((64 + lg * 16)) ^ acs);

  // B fragment read offsets per tile (hoisted out of k-loop)
  int boff0[7], boff1[7];
  #pragma unroll
  for (int tt = 0; tt < 7; ++tt){
    const int col = (t0 + tt) * 16 + lc;
    const int cs  = (col & 7) * 16;
    boff0[tt] = col * 128 + ((lg * 16) ^ cs);
    boff1[tt] = col * 128 + ((64 + lg * 16) ^ cs);
  }

  // prologue: A(0) regs + B(0) gloads   (6 VMEM outstanding)
  float4 pf[2][2];
  pf[0][0] = *(const float4*)(ag);
  pf[0][1] = *(const float4*)(ag + 4);
  #pragma unroll
  for (int j = 0; j < 4; ++j)
    GLOAD16(bsrcj[j], &lB[wid * 4096 + j * 1024]);

  f32x4 acc[7];
  #pragma unroll
  for (int t = 0; t < 7; ++t) acc[t] = (f32x4){0.f, 0.f, 0.f, 0.f};
  float ms = 0.f;

#define GEMM_STEP(KT, CUR, NXT) do {                                           \
    if ((KT) < 15){                                                            \
      pf[NXT][0] = *(const float4*)(ag + ((KT) + 1) * 64);                     \
      pf[NXT][1] = *(const float4*)(ag + ((KT) + 1) * 64 + 4);                 \
      GLOAD16(bsrcj[0] + ((KT)+1)*128, &lB[(NXT)*32768 + wid*4096 + 0*1024]);  \
      GLOAD16(bsrcj[1] + ((KT)+1)*128, &lB[(NXT)*32768 + wid*4096 + 1*1024]);  \
      GLOAD16(bsrcj[2] + ((KT)+1)*128, &lB[(NXT)*32768 + wid*4096 + 2*1024]);  \
      GLOAD16(bsrcj[3] + ((KT)+1)*128, &lB[(NXT)*32768 + wid*4096 + 3*1024]);  \
      asm volatile("s_waitcnt vmcnt(6)" ::: "memory");                         \
    } else {                                                                   \
      asm volatile("s_waitcnt vmcnt(0)" ::: "memory");                         \
    }                                                                          \
    {                                                                          \
      const float4 a0 = pf[CUR][0], a1 = pf[CUR][1];                           \
      ms += a0.x + a0.y + a0.z + a0.w + a1.x + a1.y + a1.z + a1.w;             \
      Uc u;                                                                    \
      u.h2[0] = __float22bfloat162_rn(make_float2(a0.x, a0.y));                \
      u.h2[1] = __float22bfloat162_rn(make_float2(a0.z, a0.w));                \
      u.h2[2] = __float22bfloat162_rn(make_float2(a1.x, a1.y));                \
      u.h2[3] = __float22bfloat162_rn(make_float2(a1.z, a1.w));                \
      *(short8*)(lAc + awb) = u.s8;                                            \
    }                                                                          \
    asm volatile("s_waitcnt lgkmcnt(0)" ::: "memory");                         \
    __builtin_amdgcn_s_barrier();                                              \
    __builtin_amdgcn_sched_barrier(0);                                         \
    {                                                                          \
      const short8 af0 = *(const short8*)(lAc + aoff0);                        \
      const short8 af1 = *(const short8*)(lAc + aoff1);                        \
      const char* bb = &lB[(CUR) * 32768];                                     \
      _Pragma("unroll")                                                        \
      for (int tt = 0; tt < 7; ++tt){                                          \
        if (tt < ntw){                                                         \
          const short8 bf0 = *(const short8*)(bb + boff0[tt]);                 \
          const short8 bf1 = *(const short8*)(bb + boff1[tt]);                 \
          acc[tt] = __builtin_amdgcn_mfma_f32_16x16x32_bf16(af0, bf0, acc[tt], 0, 0, 0); \
          acc[tt] = __builtin_amdgcn_mfma_f32_16x16x32_bf16(af1, bf1, acc[tt], 0, 0, 0); \
        }                                                                      \
      }                                                                        \
    }                                                                          \
    if ((KT) < 15){                                                            \
      __builtin_amdgcn_sched_barrier(0);                                       \
      __builtin_amdgcn_s_barrier();                                            \
      __builtin_amdgcn_sched_barrier(0);                                       \
    }                                                                          \
  } while (0)

  for (int m = 0; m < 8; ++m){
    const int kt0 = m * 2;
    GEMM_STEP(kt0, 0, 1);
    GEMM_STEP(kt0 + 1, 1, 0);
  }
#undef GEMM_STEP

  // row means: thread covered (row = tid>>3, k8 = tid&7); reduce over the
  // 8 consecutive lanes sharing a row.
  ms += __shfl_xor(ms, 1); ms += __shfl_xor(ms, 2); ms += __shfl_xor(ms, 4);
  if ((tid & 7) == 0) lrow[tid >> 3] = ms * (1.0f / 1024.0f);

  // epilogue: tanh + GEMM2 (in-register) + butterfly over lc
  float part[4][Kc];
  #pragma unroll
  for (int r = 0; r < 4; ++r)
    #pragma unroll
    for (int k = 0; k < Kc; ++k) part[r][k] = 0.f;

  #pragma unroll
  for (int tt = 0; tt < 7; ++tt){
    if (tt < ntw){
      const int col = (t0 + tt) * 16 + lc;
      float b1v = 0.f;
      float w2v[Kc];
      if (col < Dd){
        b1v = b1[col];
        const float4 wa = *(const float4*)(W2 + col * Kc);
        const float4 wb = *(const float4*)(W2 + col * Kc + 4);
        w2v[0] = wa.x; w2v[1] = wa.y; w2v[2] = wa.z; w2v[3] = wa.w;
        w2v[4] = wb.x; w2v[5] = wb.y; w2v[6] = wb.z; w2v[7] = wb.w;
      } else {
        #pragma unroll
        for (int k = 0; k < Kc; ++k) w2v[k] = 0.f;
      }
      #pragma unroll
      for (int r = 0; r < 4; ++r){
        const float a = tanhf(acc[tt][r] + b1v);
        #pragma unroll
        for (int k = 0; k < Kc; ++k) part[r][k] = fmaf(a, w2v[k], part[r][k]);
      }
    }
  }
  #pragma unroll
  for (int m = 1; m < 16; m <<= 1){
    #pragma unroll
    for (int r = 0; r < 4; ++r)
      #pragma unroll
      for (int k = 0; k < Kc; ++k)
        part[r][k] += __shfl_xor(part[r][k], m);
  }
  if ((lane & 15) == 0){
    #pragma unroll
    for (int r = 0; r < 4; ++r)
      #pragma unroll
      for (int k = 0; k < Kc; ++k)
        epart[wid][lg][r][k] = part[r][k];
  }
  __syncthreads();

  // combine the two wc halves, add b2, scale by row mean, store (coalesced)
  {
    const int row2 = tid >> 3, k = tid & 7;
    const int wr2 = row2 >> 4, lg2 = (row2 >> 2) & 3, r2 = row2 & 3;
    const float v = epart[wr2 * 2][lg2][r2][k] + epart[wr2 * 2 + 1][lg2][r2][k];
    sOut[(size_t)(rowBase + row2) * Kc + k] = (v + b2[k]) * lrow[row2];
  }
}

// ---------------- per-(batch,segment) channel sums
__global__ __launch_bounds__(256) void seg_sum(const float* __restrict__ s,
                                               float* __restrict__ segs){
  int b   = blockIdx.x >> 4;
  int seg = blockIdx.x & 15;
  int tid = threadIdx.x, lane = tid & 63, wid = tid >> 6;
  int l = seg * 256 + tid;
  const float4* sp = (const float4*)(s + ((long)(b * Ll + l)) * Kc);
  float4 v0 = sp[0], v1 = sp[1];
  float v[8] = {v0.x, v0.y, v0.z, v0.w, v1.x, v1.y, v1.z, v1.w};
  #pragma unroll
  for (int k = 0; k < 8; ++k){
    float x = v[k];
    x += __shfl_xor(x, 1);  x += __shfl_xor(x, 2);  x += __shfl_xor(x, 4);
    x += __shfl_xor(x, 8);  x += __shfl_xor(x, 16); x += __shfl_xor(x, 32);
    v[k] = x;
  }
  __shared__ float part[4][8];
  if (lane == 0){
    #pragma unroll
    for (int k = 0; k < 8; ++k) part[wid][k] = v[k];
  }
  __syncthreads();
  if (tid < 8){
    float t = part[0][tid] + part[1][tid] + part[2][tid] + part[3][tid];
    segs[(b * 16 + seg) * 8 + tid] = t;
  }
}

// ---------------- scan + det + softmax + log_softmax + pick -> partial loss
__global__ __launch_bounds__(256) void scan_loss(const float* __restrict__ s,
                                                 const float* __restrict__ segs,
                                                 const int* __restrict__ ptypes,
                                                 const int* __restrict__ labels,
                                                 float* __restrict__ partial){
  int b   = blockIdx.x >> 4;
  int seg = blockIdx.x & 15;
  int tid = threadIdx.x, lane = tid & 63, wid = tid >> 6;
  int l = seg * 256 + tid;

  float carry[8], T[8];
  #pragma unroll
  for (int k = 0; k < 8; ++k){ carry[k] = 0.f; T[k] = 0.f; }
  for (int ss = 0; ss < 16; ++ss){
    #pragma unroll
    for (int k = 0; k < 8; ++k){
      float x = segs[(b * 16 + ss) * 8 + k];
      T[k] += x;
      if (ss < seg) carry[k] += x;
    }
  }

  const float4* sp = (const float4*)(s + ((long)(b * Ll + l)) * Kc);
  float4 v0 = sp[0], v1 = sp[1];
  float sv[8] = {v0.x, v0.y, v0.z, v0.w, v1.x, v1.y, v1.z, v1.w};
  float P[8];
  #pragma unroll
  for (int k = 0; k < 8; ++k) P[k] = sv[k];

  #pragma unroll
  for (int st = 1; st < 64; st <<= 1){
    #pragma unroll
    for (int k = 0; k < 8; ++k){
      float u = __shfl_up(P[k], st);
      if (lane >= st) P[k] += u;
    }
  }
  __shared__ float wsum[4][8];
  if (lane == 63){
    #pragma unroll
    for (int k = 0; k < 8; ++k) wsum[wid][k] = P[k];
  }
  __syncthreads();
  for (int w = 0; w < wid; ++w){
    #pragma unroll
    for (int k = 0; k < 8; ++k) P[k] += wsum[w][k];
  }
  #pragma unroll
  for (int k = 0; k < 8; ++k) P[k] += carry[k];

  int pt = ptypes[b];
  float det[8];
  if (pt == 0){
    float inv = 1.0f / (float)(l + 1);
    #pragma unroll
    for (int k = 0; k < 8; ++k) det[k] = P[k] * inv;
  } else if (pt == 1){
    float inv = 1.0f / (float)(Ll - l);
    #pragma unroll
    for (int k = 0; k < 8; ++k) det[k] = (T[k] - P[k] + sv[k]) * inv;
  } else {
    #pragma unroll
    for (int k = 0; k < 8; ++k) det[k] = sv[k];
  }

  float mx = det[0];
  #pragma unroll
  for (int k = 1; k < 8; ++k) mx = fmaxf(mx, det[k]);
  float e[8], Z = 0.f;
  #pragma unroll
  for (int k = 0; k < 8; ++k){ e[k] = expf(det[k] - mx); Z += e[k]; }
  float invZ = 1.0f / Z;
  float p[8];
  #pragma unroll
  for (int k = 0; k < 8; ++k) p[k] = e[k] * invZ;
  float mx2 = p[0];
  #pragma unroll
  for (int k = 1; k < 8; ++k) mx2 = fmaxf(mx2, p[k]);
  float Z2 = 0.f;
  #pragma unroll
  for (int k = 0; k < 8; ++k) Z2 += expf(p[k] - mx2);
  float lse = logf(Z2) + mx2;

  int lab = labels[b * Ll + l];
  float picked = 0.f;
  #pragma unroll
  for (int k = 0; k < 8; ++k) picked = (lab == k) ? (p[k] - lse) : picked;

  float a = picked;
  a += __shfl_xor(a, 1);  a += __shfl_xor(a, 2);  a += __shfl_xor(a, 4);
  a += __shfl_xor(a, 8);  a += __shfl_xor(a, 16); a += __shfl_xor(a, 32);
  __shared__ float red[4];
  if (lane == 0) red[wid] = a;
  __syncthreads();
  if (tid == 0){
    partial[blockIdx.x] = red[0] + red[1] + red[2] + red[3];
  }
}

// ---------------- final: out[b] = -sum(partial[b*16 .. +15]) / L
__global__ __launch_bounds__(128) void final_loss(const float* __restrict__ partial,
                                                  float* __restrict__ out){
  int tid = threadIdx.x;  // 0..127 -> b = tid>>4
  float v = partial[tid];
  v += __shfl_xor(v, 1); v += __shfl_xor(v, 2);
  v += __shfl_xor(v, 4); v += __shfl_xor(v, 8);
  if ((tid & 15) == 0) out[tid >> 4] = -v * (1.0f / (float)Ll);
}

extern "C" void kernel_launch(void* const* d_in, const int* in_sizes, int n_in,
                              void* d_out, int out_size, void* d_ws, size_t ws_size,
                              hipStream_t stream){
  const float* hidd  = (const float*)d_in[0];
  const float* W1    = (const float*)d_in[1];
  const float* b1    = (const float*)d_in[2];
  const float* W2    = (const float*)d_in[3];
  const float* b2    = (const float*)d_in[4];
  const int* ptypes  = (const int*)d_in[5];
  const int* labels  = (const int*)d_in[6];
  float* out = (float*)d_out;
  char* ws = (char*)d_ws;
  if (ws_size < (size_t)WS_NEEDED) return;

  unsigned short* W1T = (unsigned short*)(ws + OFF_W1T);
  float* s       = (float*)(ws + OFF_S);
  float* segs    = (float*)(ws + OFF_SEG);
  float* partial = (float*)(ws + OFF_PART);

  prep_w1t<<<(208 * H) / 256, 256, 0, stream>>>(W1, W1T);
  gemm_fused<<<Mm / 64, 512, 0, stream>>>(hidd, W1T, b1, W2, b2, s);
  seg_sum<<<Bb * 16, 256, 0, stream>>>(s, segs);
  scan_loss<<<Bb * 16, 256, 0, stream>>>(s, segs, ptypes, labels, partial);
  final_loss<<<1, 128, 0, stream>>>(partial, out);
}